// Round 2
// baseline (199.331 us; speedup 1.0000x reference)
//
#include <hip/hip_runtime.h>
#include <math.h>

#define TTOK 8192
#define DIM  2048
#define NH   1024

// ---- workspace layout (float offsets) ----
#define OFF_PART1   0u           // [16][8192][16] = 2097152
#define OFF_LOGITS  2097152u     // [8192][16]
#define OFF_NUM     2228224u     // [8192][16]
#define OFF_COMBINE 2359296u     // [8192][16]
#define OFF_PART6   2490368u     // [256][16][2048] = 8388608
#define OFF_SRAW    10878976u    // [16][2048]
#define OFF_RAWH    10911744u    // [64][16][1024] = 1048576
#define OFF_H       11960320u    // [16][1024]
#define OFF_PART10  11976704u    // [64][16][2048] = 2097152
#define OFF_SLOTOUT 14073856u    // [16][2048]
#define OFF_CSUM    14106624u    // [128][16]
#define OFF_MUSUM   14108672u    // [64][16]
#define OFF_ENT     14109696u    // [64]
#define OFF_INVS    14109760u    // [16]

// ---- d_out layout (float offsets) ----
#define O_OUT   0u
#define O_LOSS  16777216u
#define O_GATE  16777217u
#define O_TOPI  16908289u
#define O_TOPW  16924673u
#define O_MU    16941057u
#define O_ENTR  16941073u
#define O_DISP  16941074u

__device__ __forceinline__ float wave_sum(float v){
  #pragma unroll
  for (int o=1;o<64;o<<=1) v += __shfl_xor(v,o,64);
  return v;
}

// K1: logits partials. grid 512 = 32 token-blocks x 16 k-chunks(128)
__global__ __launch_bounds__(256) void k1_logits(const float* __restrict__ x,
                                                 const float* __restrict__ Wd,
                                                 float* __restrict__ part1){
  const int tb = blockIdx.x >> 4;
  const int kc = blockIdx.x & 15;
  const int t  = tb*256 + threadIdx.x;
  const float4* __restrict__ xr = (const float4*)(x + (size_t)t*DIM + kc*128);
  float acc[16];
  #pragma unroll
  for (int e=0;e<16;e++) acc[e]=0.f;
  #pragma unroll 4
  for (int k4=0;k4<32;k4++){
    float4 xv = xr[k4];
    #pragma unroll
    for (int e=0;e<16;e++){
      float4 w = *(const float4*)(Wd + e*DIM + kc*128 + k4*4);
      acc[e] += xv.x*w.x + xv.y*w.y + xv.z*w.z + xv.w*w.w;
    }
  }
  float4* po = (float4*)(part1 + ((size_t)kc*TTOK + t)*16);
  po[0] = make_float4(acc[0],acc[1],acc[2],acc[3]);
  po[1] = make_float4(acc[4],acc[5],acc[6],acc[7]);
  po[2] = make_float4(acc[8],acc[9],acc[10],acc[11]);
  po[3] = make_float4(acc[12],acc[13],acc[14],acc[15]);
}

// K2a: logits = sum(part1); num = exp(logits) (no max-shift: |logit|<~6);
// colsum partials. grid 128 x 256, 1 float4 per thread.
__global__ __launch_bounds__(256) void k2a_num(const float* __restrict__ part1,
    float* __restrict__ logits, float* __restrict__ num, float* __restrict__ colsum_part){
  const int tid = threadIdx.x;
  const int i = blockIdx.x*256 + tid;            // [0,32768) float4 index
  const float4* p1 = (const float4*)part1;
  float4 s = make_float4(0,0,0,0);
  #pragma unroll
  for (int kc=0;kc<16;kc++){
    float4 v = p1[(size_t)kc*32768 + i];
    s.x+=v.x; s.y+=v.y; s.z+=v.z; s.w+=v.w;
  }
  ((float4*)logits)[i] = s;
  float4 n = make_float4(expf(s.x),expf(s.y),expf(s.z),expf(s.w));
  ((float4*)num)[i] = n;
  // reduce n across lanes with same q=(tid&3) -> per-expert-group sums
  #pragma unroll
  for (int o=4;o<64;o<<=1){
    n.x += __shfl_xor(n.x,o,64); n.y += __shfl_xor(n.y,o,64);
    n.z += __shfl_xor(n.z,o,64); n.w += __shfl_xor(n.w,o,64);
  }
  __shared__ float4 red[4][4];
  const int w = tid>>6, lane = tid&63;
  if (lane<4) red[w][lane] = n;
  __syncthreads();
  if (tid<4){
    float4 a = red[0][tid], b = red[1][tid], c = red[2][tid], d = red[3][tid];
    float4 t = make_float4(a.x+b.x+c.x+d.x, a.y+b.y+c.y+d.y,
                           a.z+b.z+c.z+d.z, a.w+b.w+c.w+d.w);
    *(float4*)(colsum_part + blockIdx.x*16 + tid*4) = t;
  }
}

// K5: inv_s = 1/colsum. 1 block x 256
__global__ __launch_bounds__(256) void k5_invs(const float* __restrict__ colsum_part,
                                               float* __restrict__ inv_s){
  const int tid = threadIdx.x;
  const int e = tid&15, sl = tid>>4;             // 16 slices x 8 blocks each
  float s = 0.f;
  #pragma unroll
  for (int k=0;k<8;k++) s += colsum_part[(sl*8+k)*16 + e];
  __shared__ float L[16][16];
  L[sl][e] = s;
  __syncthreads();
  if (tid<16){
    float v=0.f;
    #pragma unroll
    for (int q=0;q<16;q++) v += L[q][tid];
    inv_s[tid] = 1.f/v;
  }
}

// K2b: row softmax -> combine/gate/topk; musum/ent partials. grid 64 x 128
__global__ __launch_bounds__(128) void k2b_row(const float* __restrict__ logits,
    float* __restrict__ combine, float* __restrict__ gate_out,
    float* __restrict__ topi_out, float* __restrict__ topw_out,
    float* __restrict__ musum_part, float* __restrict__ ent_part){
  const int tid = threadIdx.x;
  const int t = blockIdx.x*128 + tid;
  float l[16];
  const float4* lr = (const float4*)(logits + (size_t)t*16);
  #pragma unroll
  for (int q=0;q<4;q++){ float4 v=lr[q]; l[q*4]=v.x; l[q*4+1]=v.y; l[q*4+2]=v.z; l[q*4+3]=v.w; }
  float m = l[0];
  #pragma unroll
  for (int e=1;e<16;e++) m = fmaxf(m,l[e]);
  float c[16]; float s=0.f;
  #pragma unroll
  for (int e=0;e<16;e++){ c[e]=expf(l[e]-m); s+=c[e]; }
  float inv = 1.f/s;
  #pragma unroll
  for (int e=0;e<16;e++) c[e]*=inv;
  float4* co = (float4*)(combine + (size_t)t*16);
  co[0]=make_float4(c[0],c[1],c[2],c[3]);   co[1]=make_float4(c[4],c[5],c[6],c[7]);
  co[2]=make_float4(c[8],c[9],c[10],c[11]); co[3]=make_float4(c[12],c[13],c[14],c[15]);
  float* go = gate_out + (size_t)t*16;
  #pragma unroll
  for (int e=0;e<16;e++) go[e]=c[e];
  float v0=-1.f, v1=-1.f; int i0=0, i1=0;
  #pragma unroll
  for (int e=0;e<16;e++){
    float ce=c[e];
    if (ce>v0){ v1=v0; i1=i0; v0=ce; i0=e; }
    else if (ce>v1){ v1=ce; i1=e; }
  }
  float dn = fmaxf(v0+v1, 1e-8f);
  topi_out[(size_t)t*2+0]=(float)i0; topi_out[(size_t)t*2+1]=(float)i1;
  topw_out[(size_t)t*2+0]=v0/dn;     topw_out[(size_t)t*2+1]=v1/dn;
  float ent=0.f;
  #pragma unroll
  for (int e=0;e<16;e++) ent -= c[e]*logf(c[e]+1e-8f);

  __shared__ float red[2][16];
  __shared__ float rede[2];
  const int w = tid>>6, lane = tid&63;
  #pragma unroll
  for (int e=0;e<16;e++){ float v=wave_sum(c[e]); if(lane==0) red[w][e]=v; }
  { float v=wave_sum(ent); if(lane==0) rede[w]=v; }
  __syncthreads();
  if (tid<16) musum_part[blockIdx.x*16+tid]=red[0][tid]+red[1][tid];
  if (tid==16) ent_part[blockIdx.x]=rede[0]+rede[1];
}

// K3: mean_usage, entropy, p from Wd, router_loss. 1 block x 256
__global__ __launch_bounds__(256) void k3_finalize(const float* __restrict__ Wd,
    const float* __restrict__ musum_part, const float* __restrict__ ent_part,
    float* __restrict__ loss_out, float* __restrict__ mu_out, float* __restrict__ ent_out){
  const int tid = threadIdx.x;
  __shared__ float sq[16][16];
  __shared__ float smu[16];
  __shared__ float sqe[16];
  {
    int s = tid>>4, e = tid&15;
    const float* base = Wd + (size_t)s*DIM + e*128;
    float q=0.f;
    for (int i=0;i<128;i+=4){ float4 v=*(const float4*)(base+i); q+=v.x+v.y+v.z+v.w; }
    sq[s][e]=q;
  }
  if (tid<16){
    float mu=0.f;
    for (int b=0;b<64;b++) mu += musum_part[b*16+tid];
    mu/=8192.f;
    mu_out[tid]=mu; smu[tid]=mu;
  }
  if (tid==32){ float es=0.f; for(int b=0;b<64;b++) es+=ent_part[b]; ent_out[0]=es/8192.f; }
  __syncthreads();
  __shared__ float sqv[16];
  if (tid<16){ float q=0.f; for(int s=0;s<16;s++) q+=sq[s][tid]; sqv[tid]=q/2048.f; }
  __syncthreads();
  if (tid<16){
    float qm=-INFINITY;
    for (int e=0;e<16;e++) qm=fmaxf(qm,sqv[e]);
    sqe[tid]=expf(sqv[tid]-qm);
  }
  __syncthreads();
  if (tid==0){
    float qs=0.f; for(int e=0;e<16;e++) qs+=sqe[e];
    float loss=0.f; for(int e=0;e<16;e++) loss+=smu[e]*(sqe[e]/qs);
    loss_out[0]=16.f*loss;
  }
}

// K5b: dispatch output. grid 512 x 256
__global__ __launch_bounds__(256) void k5b_disp(const float* __restrict__ num,
    const float* __restrict__ inv_s, float* __restrict__ disp_out){
  int i = blockIdx.x*256 + threadIdx.x;
  disp_out[i] = num[i]*inv_s[i&15];
}

// K6: part6[tc][e][d] = sum_{t in tc} num[t][e]*x[t][d]. grid 512 = 256tc(32tok) x 2dc
__global__ __launch_bounds__(256) void k6_slotin(const float* __restrict__ x,
    const float* __restrict__ num, float* __restrict__ part6){
  const int tc = blockIdx.x >> 1;
  const int dc = blockIdx.x & 1;
  const int d  = dc*1024 + threadIdx.x*4;
  const int t0 = tc*32;
  __shared__ float4 sN[128];                      // num[t0..t0+31][0..15]
  if (threadIdx.x < 128) sN[threadIdx.x] = ((const float4*)num)[t0*4 + threadIdx.x];
  __syncthreads();
  float4 acc[16];
  #pragma unroll
  for (int e=0;e<16;e++) acc[e]=make_float4(0,0,0,0);
  #pragma unroll 2
  for (int t=0;t<32;t++){
    const float4 xv = *(const float4*)(x + (size_t)(t0+t)*DIM + d);
    #pragma unroll
    for (int q=0;q<4;q++){
      float4 nq = sN[t*4+q];
      acc[q*4+0].x=fmaf(nq.x,xv.x,acc[q*4+0].x); acc[q*4+0].y=fmaf(nq.x,xv.y,acc[q*4+0].y);
      acc[q*4+0].z=fmaf(nq.x,xv.z,acc[q*4+0].z); acc[q*4+0].w=fmaf(nq.x,xv.w,acc[q*4+0].w);
      acc[q*4+1].x=fmaf(nq.y,xv.x,acc[q*4+1].x); acc[q*4+1].y=fmaf(nq.y,xv.y,acc[q*4+1].y);
      acc[q*4+1].z=fmaf(nq.y,xv.z,acc[q*4+1].z); acc[q*4+1].w=fmaf(nq.y,xv.w,acc[q*4+1].w);
      acc[q*4+2].x=fmaf(nq.z,xv.x,acc[q*4+2].x); acc[q*4+2].y=fmaf(nq.z,xv.y,acc[q*4+2].y);
      acc[q*4+2].z=fmaf(nq.z,xv.z,acc[q*4+2].z); acc[q*4+2].w=fmaf(nq.z,xv.w,acc[q*4+2].w);
      acc[q*4+3].x=fmaf(nq.w,xv.x,acc[q*4+3].x); acc[q*4+3].y=fmaf(nq.w,xv.y,acc[q*4+3].y);
      acc[q*4+3].z=fmaf(nq.w,xv.z,acc[q*4+3].z); acc[q*4+3].w=fmaf(nq.w,xv.w,acc[q*4+3].w);
    }
  }
  #pragma unroll
  for (int e=0;e<16;e++)
    *(float4*)(part6 + ((size_t)tc*16+e)*DIM + d) = acc[e];
}

// K7: slot_raw = inv_s * sum_tc part6. grid 256 x 256 (2-way tc split per block)
__global__ __launch_bounds__(256) void k7_sraw(const float* __restrict__ part6,
    const float* __restrict__ inv_s, float* __restrict__ slot_raw){
  const int tid = threadIdx.x;
  const int half = tid>>7, il = tid&127;
  const int i = blockIdx.x*128 + il;             // [0,32768)
  float s=0.f;
  #pragma unroll 8
  for (int tc=half*128; tc<half*128+128; tc++) s += part6[(size_t)tc*32768 + i];
  __shared__ float s2[256];
  s2[tid]=s;
  __syncthreads();
  if (tid<128){
    int ii = blockIdx.x*128 + tid;
    slot_raw[ii] = inv_s[ii>>11]*(s2[tid]+s2[tid+128]);
  }
}

// K8: rawh[dc][e][h] = sum_{d in dc} slot_raw[e][d]*W1[e][d][h]. grid 1024 = 16e x 64dc
__global__ __launch_bounds__(256) void k8_h(const float* __restrict__ slot_raw,
    const float* __restrict__ W1, float* __restrict__ rawh){
  const int e  = blockIdx.x >> 6;
  const int dc = blockIdx.x & 63;
  const int dbase = dc*32;
  float sl[32];
  #pragma unroll
  for (int d=0;d<32;d++) sl[d] = slot_raw[e*DIM + dbase + d];
  const int hq = threadIdx.x*4;
  float4 acc = make_float4(0,0,0,0);
  #pragma unroll
  for (int d=0;d<32;d++){
    float4 w = *(const float4*)(W1 + ((size_t)e*DIM + dbase + d)*NH + hq);
    float s = sl[d];
    acc.x=fmaf(s,w.x,acc.x); acc.y=fmaf(s,w.y,acc.y);
    acc.z=fmaf(s,w.z,acc.z); acc.w=fmaf(s,w.w,acc.w);
  }
  *(float4*)(rawh + ((size_t)dc*16+e)*NH + hq) = acc;
}

// K9: h = gelu(sum_dc rawh + b1). grid 64 x 256
__global__ __launch_bounds__(256) void k9_gelu(const float* __restrict__ rawh,
    const float* __restrict__ b1, float* __restrict__ hbuf){
  const int i = blockIdx.x*256 + threadIdx.x;    // [0,16384)
  float s=0.f;
  #pragma unroll 8
  for (int dc=0;dc<64;dc++) s += rawh[(size_t)dc*16384 + i];
  float pre = s + b1[i];
  hbuf[i] = 0.5f*pre*(1.f+erff(pre*0.70710678118654752f));
}

// K10: part10[hc][e][d] = sum_{h in hc} h[e][h]*W2[e][h][d]. grid 1024 = 16e x 64hc
__global__ __launch_bounds__(256) void k10_so(const float* __restrict__ hbuf,
    const float* __restrict__ W2, float* __restrict__ part10){
  const int e  = blockIdx.x >> 6;
  const int hc = blockIdx.x & 63;
  const int hbase = hc*16;
  float hh[16];
  #pragma unroll
  for (int j=0;j<16;j++) hh[j] = hbuf[e*NH + hbase + j];
  const int d0 = threadIdx.x*4, d1 = d0 + 1024;
  float4 a0=make_float4(0,0,0,0), a1=make_float4(0,0,0,0);
  #pragma unroll
  for (int j=0;j<16;j++){
    const float* wrow = W2 + ((size_t)e*NH + hbase + j)*DIM;
    float4 w0 = *(const float4*)(wrow + d0);
    float4 w1 = *(const float4*)(wrow + d1);
    float s = hh[j];
    a0.x=fmaf(s,w0.x,a0.x); a0.y=fmaf(s,w0.y,a0.y); a0.z=fmaf(s,w0.z,a0.z); a0.w=fmaf(s,w0.w,a0.w);
    a1.x=fmaf(s,w1.x,a1.x); a1.y=fmaf(s,w1.y,a1.y); a1.z=fmaf(s,w1.z,a1.z); a1.w=fmaf(s,w1.w,a1.w);
  }
  *(float4*)(part10 + ((size_t)hc*16+e)*DIM + d0) = a0;
  *(float4*)(part10 + ((size_t)hc*16+e)*DIM + d1) = a1;
}

// K11: slot_out = sum_hc part10 + b2. grid 256 x 256 (2-way hc split)
__global__ __launch_bounds__(256) void k11_sofin(const float* __restrict__ part10,
    const float* __restrict__ b2, float* __restrict__ slot_out){
  const int tid = threadIdx.x;
  const int half = tid>>7, il = tid&127;
  const int i = blockIdx.x*128 + il;             // [0,32768)
  float s=0.f;
  #pragma unroll 8
  for (int hc=half*32; hc<half*32+32; hc++) s += part10[(size_t)hc*32768 + i];
  __shared__ float s2[256];
  s2[tid]=s;
  __syncthreads();
  if (tid<128){
    int ii = blockIdx.x*128 + tid;
    slot_out[ii] = s2[tid]+s2[tid+128] + b2[ii];
  }
}

// K12: out = combine @ slot_out. grid 1024 = 512tb(16tok) x 2dc
__global__ __launch_bounds__(256) void k12_out(const float* __restrict__ slot_out,
    const float* __restrict__ combine, float* __restrict__ out){
  const int tb = blockIdx.x >> 1;
  const int dc = blockIdx.x & 1;
  const int t0 = tb*16;
  const int d  = dc*1024 + threadIdx.x*4;
  float4 sv[16];
  #pragma unroll
  for (int e=0;e<16;e++) sv[e] = *(const float4*)(slot_out + (size_t)e*DIM + d);
  #pragma unroll 2
  for (int t=0;t<16;t++){
    const float* cr = combine + (size_t)(t0+t)*16;
    float4 a = make_float4(0,0,0,0);
    #pragma unroll
    for (int e=0;e<16;e++){
      float c = cr[e];
      a.x=fmaf(c,sv[e].x,a.x); a.y=fmaf(c,sv[e].y,a.y);
      a.z=fmaf(c,sv[e].z,a.z); a.w=fmaf(c,sv[e].w,a.w);
    }
    *(float4*)(out + (size_t)(t0+t)*DIM + d) = a;
  }
}

extern "C" void kernel_launch(void* const* d_in, const int* in_sizes, int n_in,
                              void* d_out, int out_size, void* d_ws, size_t ws_size,
                              hipStream_t stream) {
  const float* x  = (const float*)d_in[0];
  const float* Wd = (const float*)d_in[1];
  const float* W1 = (const float*)d_in[2];
  const float* b1 = (const float*)d_in[3];
  const float* W2 = (const float*)d_in[4];
  const float* b2 = (const float*)d_in[5];
  float* out = (float*)d_out;
  float* ws  = (float*)d_ws;

  float* part1   = ws + OFF_PART1;
  float* logits  = ws + OFF_LOGITS;
  float* num     = ws + OFF_NUM;
  float* combine = ws + OFF_COMBINE;
  float* part6   = ws + OFF_PART6;
  float* sraw    = ws + OFF_SRAW;
  float* rawh    = ws + OFF_RAWH;
  float* hbuf    = ws + OFF_H;
  float* part10  = ws + OFF_PART10;
  float* slot_out= ws + OFF_SLOTOUT;
  float* csump   = ws + OFF_CSUM;
  float* musump  = ws + OFF_MUSUM;
  float* entp    = ws + OFF_ENT;
  float* inv_s   = ws + OFF_INVS;

  k1_logits<<<512, 256, 0, stream>>>(x, Wd, part1);
  k2a_num<<<128, 256, 0, stream>>>(part1, logits, num, csump);
  k5_invs<<<1, 256, 0, stream>>>(csump, inv_s);
  k2b_row<<<64, 128, 0, stream>>>(logits, combine, out + O_GATE, out + O_TOPI,
                                  out + O_TOPW, musump, entp);
  k3_finalize<<<1, 256, 0, stream>>>(Wd, musump, entp, out + O_LOSS, out + O_MU, out + O_ENTR);
  k5b_disp<<<512, 256, 0, stream>>>(num, inv_s, out + O_DISP);
  k6_slotin<<<512, 256, 0, stream>>>(x, num, part6);
  k7_sraw<<<256, 256, 0, stream>>>(part6, inv_s, sraw);
  k8_h<<<1024, 256, 0, stream>>>(sraw, W1, rawh);
  k9_gelu<<<64, 256, 0, stream>>>(rawh, b1, hbuf);
  k10_so<<<1024, 256, 0, stream>>>(hbuf, W2, part10);
  k11_sofin<<<256, 256, 0, stream>>>(part10, b2, slot_out);
  k12_out<<<1024, 256, 0, stream>>>(slot_out, combine, out + O_OUT);
}

// Round 3
// 179.157 us; speedup vs baseline: 1.1126x; 1.1126x over previous
//
#include <hip/hip_runtime.h>
#include <math.h>

#define TTOK 8192
#define DIM  2048
#define NH   1024

// ---- workspace layout (float offsets) ----
#define OFF_PART1   0u           // [16][8192][16] = 2097152
#define OFF_NUM     2097152u     // [8192][16]
#define OFF_COMBINE 2228224u     // [8192][16]
#define OFF_CSUM    2359296u     // [128][16]
#define OFF_MUSUM   2361344u     // [128][16]
#define OFF_ENT     2363392u     // [128]
#define OFF_PART6   2363520u     // [256][16][2048] = 8388608
#define OFF_SRAW    10752128u    // [16][2048]
#define OFF_HBUF    10784896u    // [16][1024]
#define OFF_SLOT    10801280u    // [16][2048]

// ---- d_out layout (float offsets) ----
#define O_OUT   0u
#define O_LOSS  16777216u
#define O_GATE  16777217u
#define O_TOPI  16908289u
#define O_TOPW  16924673u
#define O_MU    16941057u
#define O_ENTR  16941073u
#define O_DISP  16941074u

__device__ __forceinline__ float wave_sum(float v){
  #pragma unroll
  for (int o=1;o<64;o<<=1) v += __shfl_xor(v,o,64);
  return v;
}

// KA: logits partials. grid 512 = 32 token-blocks x 16 k-chunks(128)
__global__ __launch_bounds__(256) void ka_logits(const float* __restrict__ x,
                                                 const float* __restrict__ Wd,
                                                 float* __restrict__ part1){
  const int tb = blockIdx.x >> 4;
  const int kc = blockIdx.x & 15;
  const int t  = tb*256 + threadIdx.x;
  const float4* __restrict__ xr = (const float4*)(x + (size_t)t*DIM + kc*128);
  float acc[16];
  #pragma unroll
  for (int e=0;e<16;e++) acc[e]=0.f;
  #pragma unroll 4
  for (int k4=0;k4<32;k4++){
    float4 xv = xr[k4];
    #pragma unroll
    for (int e=0;e<16;e++){
      float4 w = *(const float4*)(Wd + e*DIM + kc*128 + k4*4);
      acc[e] += xv.x*w.x + xv.y*w.y + xv.z*w.z + xv.w*w.w;
    }
  }
  float4* po = (float4*)(part1 + ((size_t)kc*TTOK + t)*16);
  po[0] = make_float4(acc[0],acc[1],acc[2],acc[3]);
  po[1] = make_float4(acc[4],acc[5],acc[6],acc[7]);
  po[2] = make_float4(acc[8],acc[9],acc[10],acc[11]);
  po[3] = make_float4(acc[12],acc[13],acc[14],acc[15]);
}

// KB: reduce part1 -> logits (registers+LDS only); num=exp(logits); csum partials;
// row softmax -> combine/gate/topk; musum/ent partials. grid 128 x 256 (64 tok/blk)
__global__ __launch_bounds__(256) void kb_router(const float* __restrict__ part1,
    float* __restrict__ num, float* __restrict__ csum_part,
    float* __restrict__ combine, float* __restrict__ gate_out,
    float* __restrict__ topi_out, float* __restrict__ topw_out,
    float* __restrict__ musum_part, float* __restrict__ ent_part){
  const int tid = threadIdx.x;
  const int i = blockIdx.x*256 + tid;            // float4 idx over [8192][16]/4
  const float4* p1 = (const float4*)part1;
  float4 s = make_float4(0,0,0,0);
  #pragma unroll
  for (int kc=0;kc<16;kc++){
    float4 v = p1[(size_t)kc*32768 + i];
    s.x+=v.x; s.y+=v.y; s.z+=v.z; s.w+=v.w;
  }
  float4 n4 = make_float4(expf(s.x),expf(s.y),expf(s.z),expf(s.w));
  ((float4*)num)[i] = n4;
  __shared__ float Lg[64][20];
  const int tl = tid>>2, q = tid&3;
  *(float4*)(&Lg[tl][q*4]) = s;
  // csum partial: reduce n4 across lanes with same q
  float4 n = n4;
  #pragma unroll
  for (int o=4;o<64;o<<=1){
    n.x += __shfl_xor(n.x,o,64); n.y += __shfl_xor(n.y,o,64);
    n.z += __shfl_xor(n.z,o,64); n.w += __shfl_xor(n.w,o,64);
  }
  __shared__ float4 red[4][4];
  const int w = tid>>6, lane = tid&63;
  if (lane<4) red[w][lane] = n;
  __syncthreads();
  if (tid<4){
    float4 a=red[0][tid],b=red[1][tid],c=red[2][tid],d=red[3][tid];
    *(float4*)(csum_part + blockIdx.x*16 + tid*4) =
      make_float4(a.x+b.x+c.x+d.x, a.y+b.y+c.y+d.y, a.z+b.z+c.z+d.z, a.w+b.w+c.w+d.w);
  }
  // softmax phase: wave 0 handles 64 tokens
  if (tid < 64){
    const int gt = blockIdx.x*64 + tid;
    float l[16];
    #pragma unroll
    for (int e=0;e<16;e++) l[e] = Lg[tid][e];
    float m = l[0];
    #pragma unroll
    for (int e=1;e<16;e++) m = fmaxf(m,l[e]);
    float c[16]; float sm=0.f;
    #pragma unroll
    for (int e=0;e<16;e++){ c[e]=expf(l[e]-m); sm+=c[e]; }
    float inv = 1.f/sm;
    #pragma unroll
    for (int e=0;e<16;e++) c[e]*=inv;
    float4* co = (float4*)(combine + (size_t)gt*16);
    co[0]=make_float4(c[0],c[1],c[2],c[3]);   co[1]=make_float4(c[4],c[5],c[6],c[7]);
    co[2]=make_float4(c[8],c[9],c[10],c[11]); co[3]=make_float4(c[12],c[13],c[14],c[15]);
    float* go = gate_out + (size_t)gt*16;
    #pragma unroll
    for (int e=0;e<16;e++) go[e]=c[e];
    float v0=-1.f, v1=-1.f; int i0=0, i1=0;
    #pragma unroll
    for (int e=0;e<16;e++){
      float ce=c[e];
      if (ce>v0){ v1=v0; i1=i0; v0=ce; i0=e; }
      else if (ce>v1){ v1=ce; i1=e; }
    }
    float dn = fmaxf(v0+v1, 1e-8f);
    topi_out[(size_t)gt*2+0]=(float)i0; topi_out[(size_t)gt*2+1]=(float)i1;
    topw_out[(size_t)gt*2+0]=v0/dn;     topw_out[(size_t)gt*2+1]=v1/dn;
    float ent=0.f;
    #pragma unroll
    for (int e=0;e<16;e++) ent -= c[e]*logf(c[e]+1e-8f);
    #pragma unroll
    for (int e=0;e<16;e++){
      float v = wave_sum(c[e]);
      if (tid==0) musum_part[blockIdx.x*16+e] = v;
    }
    float ve = wave_sum(ent);
    if (tid==0) ent_part[blockIdx.x] = ve;
  }
}

// KD: part6[tc][e][d] = sum_{t in tc} num[t][e]*x[t][d]; dc==0 blocks also write
// dispatch; block 0 also does inv_s/mu/ent/p/loss finalize. grid 512 = 256tc x 2dc
__global__ __launch_bounds__(256) void kd_slotin(const float* __restrict__ x,
    const float* __restrict__ num, const float* __restrict__ csum_part,
    const float* __restrict__ musum_part, const float* __restrict__ ent_part,
    const float* __restrict__ Wd,
    float* __restrict__ part6, float* __restrict__ disp_out,
    float* __restrict__ loss_out, float* __restrict__ mu_out, float* __restrict__ ent_out){
  const int tc = blockIdx.x >> 1;
  const int dc = blockIdx.x & 1;
  const int tid = threadIdx.x;
  const int d  = dc*1024 + tid*4;
  const int t0 = tc*32;
  __shared__ float4 sN[128];                      // num[t0..t0+31][0..15]
  if (tid < 128) sN[tid] = ((const float4*)num)[t0*4 + tid];
  __syncthreads();
  float4 acc[16];
  #pragma unroll
  for (int e=0;e<16;e++) acc[e]=make_float4(0,0,0,0);
  #pragma unroll 2
  for (int t=0;t<32;t++){
    const float4 xv = *(const float4*)(x + (size_t)(t0+t)*DIM + d);
    #pragma unroll
    for (int qq=0;qq<4;qq++){
      float4 nq = sN[t*4+qq];
      acc[qq*4+0].x=fmaf(nq.x,xv.x,acc[qq*4+0].x); acc[qq*4+0].y=fmaf(nq.x,xv.y,acc[qq*4+0].y);
      acc[qq*4+0].z=fmaf(nq.x,xv.z,acc[qq*4+0].z); acc[qq*4+0].w=fmaf(nq.x,xv.w,acc[qq*4+0].w);
      acc[qq*4+1].x=fmaf(nq.y,xv.x,acc[qq*4+1].x); acc[qq*4+1].y=fmaf(nq.y,xv.y,acc[qq*4+1].y);
      acc[qq*4+1].z=fmaf(nq.y,xv.z,acc[qq*4+1].z); acc[qq*4+1].w=fmaf(nq.y,xv.w,acc[qq*4+1].w);
      acc[qq*4+2].x=fmaf(nq.z,xv.x,acc[qq*4+2].x); acc[qq*4+2].y=fmaf(nq.z,xv.y,acc[qq*4+2].y);
      acc[qq*4+2].z=fmaf(nq.z,xv.z,acc[qq*4+2].z); acc[qq*4+2].w=fmaf(nq.z,xv.w,acc[qq*4+2].w);
      acc[qq*4+3].x=fmaf(nq.w,xv.x,acc[qq*4+3].x); acc[qq*4+3].y=fmaf(nq.w,xv.y,acc[qq*4+3].y);
      acc[qq*4+3].z=fmaf(nq.w,xv.z,acc[qq*4+3].z); acc[qq*4+3].w=fmaf(nq.w,xv.w,acc[qq*4+3].w);
    }
  }
  #pragma unroll
  for (int e=0;e<16;e++)
    *(float4*)(part6 + ((size_t)tc*16+e)*DIM + d) = acc[e];

  if (dc==0){
    // dispatch rows for this tc (needs inv_s from csum partials)
    __shared__ float sIv[16][16];
    __shared__ float sInv[16];
    { int g = tid>>4, e = tid&15;
      float v=0.f;
      #pragma unroll
      for (int k=0;k<8;k++) v += csum_part[(g*8+k)*16 + e];
      sIv[g][e]=v; }
    __syncthreads();
    if (tid<16){
      float v=0.f;
      #pragma unroll
      for (int g2=0;g2<16;g2++) v+=sIv[g2][tid];
      sInv[tid]=1.f/v;
    }
    __syncthreads();
    const float* sNf = (const float*)sN;
    const int j = tid*2;
    float2 dv = make_float2(sNf[j]*sInv[j&15], sNf[j+1]*sInv[(j+1)&15]);
    *(float2*)(disp_out + (size_t)t0*16 + j) = dv;

    if (tc==0){
      // finalize: mean_usage, entropy, p from Wd, router_loss
      __shared__ float sq[16][16];
      __shared__ float smu[16];
      __shared__ float sqv[16];
      __shared__ float sqe[16];
      {
        int s = tid>>4, ch = tid&15;
        const float* base = Wd + (size_t)s*DIM + ch*128;
        float qv=0.f;
        for (int ii=0;ii<128;ii+=4){ float4 v=*(const float4*)(base+ii); qv+=v.x+v.y+v.z+v.w; }
        sq[s][ch]=qv;
      }
      if (tid<16){
        float mu=0.f;
        for (int b=0;b<128;b++) mu += musum_part[b*16+tid];
        mu/=8192.f;
        mu_out[tid]=mu; smu[tid]=mu;
      }
      if (tid==32){ float es=0.f; for(int b=0;b<128;b++) es+=ent_part[b]; ent_out[0]=es/8192.f; }
      __syncthreads();
      if (tid<16){ float qv=0.f; for(int s=0;s<16;s++) qv+=sq[s][tid]; sqv[tid]=qv/2048.f; }
      __syncthreads();
      if (tid<16){
        float qm=-INFINITY;
        for (int e=0;e<16;e++) qm=fmaxf(qm,sqv[e]);
        sqe[tid]=expf(sqv[tid]-qm);
      }
      __syncthreads();
      if (tid==0){
        float qs=0.f; for(int e=0;e<16;e++) qs+=sqe[e];
        float loss=0.f; for(int e=0;e<16;e++) loss+=smu[e]*(sqe[e]/qs);
        loss_out[0]=16.f*loss;
      }
    }
  }
}

// KE: sraw_raw[i] = sum_tc part6[tc][i] (inv_s applied later in KF). grid 256 x 256
__global__ __launch_bounds__(256) void ke_sraw(const float* __restrict__ part6,
    float* __restrict__ sraw){
  const int tid = threadIdx.x;
  const int half = tid>>7, il = tid&127;
  const int i = blockIdx.x*128 + il;             // [0,32768)
  float s=0.f;
  #pragma unroll 8
  for (int tc=half*128; tc<half*128+128; tc++) s += part6[(size_t)tc*32768 + i];
  __shared__ float s2[256];
  s2[tid]=s;
  __syncthreads();
  if (tid<128){
    int ii = blockIdx.x*128 + tid;
    sraw[ii] = s2[tid]+s2[tid+128];
  }
}

// KF: h[e][hbase+hl] = gelu(inv_s[e]*sum_d sraw[e][d]*W1[e][d][h] + b1).
// grid 512 = 16e x 32hc(32-wide), full-K loop, sraw staged in LDS.
__global__ __launch_bounds__(256) void kf_h(const float* __restrict__ sraw,
    const float* __restrict__ W1, const float* __restrict__ b1,
    const float* __restrict__ csum_part, float* __restrict__ hbuf){
  const int e  = blockIdx.x >> 5;
  const int hc = blockIdx.x & 31;
  const int hbase = hc*32;
  const int tid = threadIdx.x;
  __shared__ float sr[2048];
  __shared__ float sacc[256];
  __shared__ float sIpart[2];
  { const float4* s4 = (const float4*)(sraw + (size_t)e*DIM);
    float4 a = s4[tid*2], b = s4[tid*2+1];
    *(float4*)(&sr[tid*8]) = a; *(float4*)(&sr[tid*8+4]) = b; }
  if (tid < 128){
    float v = csum_part[tid*16 + e];
    #pragma unroll
    for (int o=1;o<64;o<<=1) v += __shfl_xor(v,o,64);
    if ((tid&63)==0) sIpart[tid>>6] = v;
  }
  __syncthreads();
  const int hl = tid&31, ds = tid>>5;            // ds in [0,8)
  float acc = 0.f;
  const float* wp = W1 + (size_t)e*DIM*NH + hbase + hl;
  #pragma unroll 16
  for (int d2=0; d2<256; d2++){
    const int dd = d2*8 + ds;
    acc = fmaf(sr[dd], wp[(size_t)dd*NH], acc);
  }
  sacc[tid] = acc;
  __syncthreads();
  if (tid < 32){
    float s = 0.f;
    #pragma unroll
    for (int k=0;k<8;k++) s += sacc[k*32 + tid];
    float invs = 1.f/(sIpart[0]+sIpart[1]);
    float pre = invs*s + b1[(size_t)e*NH + hbase + tid];
    hbuf[(size_t)e*NH + hbase + tid] = 0.5f*pre*(1.f+erff(pre*0.70710678118654752f));
  }
}

// KG: slot_out[e][dbase+dl] = sum_h h[e][h]*W2[e][h][d] + b2.
// grid 512 = 16e x 32dc(64-wide), full-K loop, h staged in LDS.
__global__ __launch_bounds__(256) void kg_so(const float* __restrict__ hbuf,
    const float* __restrict__ W2, const float* __restrict__ b2,
    float* __restrict__ slot_out){
  const int e  = blockIdx.x >> 5;
  const int dc = blockIdx.x & 31;
  const int dbase = dc*64;
  const int tid = threadIdx.x;
  __shared__ float hh[1024];
  __shared__ float sacc[256];
  { const float4* h4 = (const float4*)(hbuf + (size_t)e*NH);
    *(float4*)(&hh[tid*4]) = h4[tid]; }
  __syncthreads();
  const int dl = tid&63, hs = tid>>6;            // hs in [0,4)
  float acc = 0.f;
  const float* wp = W2 + (size_t)e*NH*DIM + dbase + dl;
  #pragma unroll 16
  for (int h2=0; h2<256; h2++){
    const int hidx = h2*4 + hs;
    acc = fmaf(hh[hidx], wp[(size_t)hidx*DIM], acc);
  }
  sacc[tid] = acc;
  __syncthreads();
  if (tid < 64){
    float s = sacc[tid] + sacc[64+tid] + sacc[128+tid] + sacc[192+tid];
    slot_out[(size_t)e*DIM + dbase + tid] = s + b2[(size_t)e*DIM + dbase + tid];
  }
}

// KH: out = combine @ slot_out. grid 1024 = 512tb(16tok) x 2dc
__global__ __launch_bounds__(256) void kh_out(const float* __restrict__ slot_out,
    const float* __restrict__ combine, float* __restrict__ out){
  const int tb = blockIdx.x >> 1;
  const int dc = blockIdx.x & 1;
  const int t0 = tb*16;
  const int d  = dc*1024 + threadIdx.x*4;
  float4 sv[16];
  #pragma unroll
  for (int e=0;e<16;e++) sv[e] = *(const float4*)(slot_out + (size_t)e*DIM + d);
  #pragma unroll 2
  for (int t=0;t<16;t++){
    const float* cr = combine + (size_t)(t0+t)*16;
    float4 a = make_float4(0,0,0,0);
    #pragma unroll
    for (int e=0;e<16;e++){
      float c = cr[e];
      a.x=fmaf(c,sv[e].x,a.x); a.y=fmaf(c,sv[e].y,a.y);
      a.z=fmaf(c,sv[e].z,a.z); a.w=fmaf(c,sv[e].w,a.w);
    }
    *(float4*)(out + (size_t)(t0+t)*DIM + d) = a;
  }
}

extern "C" void kernel_launch(void* const* d_in, const int* in_sizes, int n_in,
                              void* d_out, int out_size, void* d_ws, size_t ws_size,
                              hipStream_t stream) {
  const float* x  = (const float*)d_in[0];
  const float* Wd = (const float*)d_in[1];
  const float* W1 = (const float*)d_in[2];
  const float* b1 = (const float*)d_in[3];
  const float* W2 = (const float*)d_in[4];
  const float* b2 = (const float*)d_in[5];
  float* out = (float*)d_out;
  float* ws  = (float*)d_ws;

  float* part1   = ws + OFF_PART1;
  float* num     = ws + OFF_NUM;
  float* combine = ws + OFF_COMBINE;
  float* csump   = ws + OFF_CSUM;
  float* musump  = ws + OFF_MUSUM;
  float* entp    = ws + OFF_ENT;
  float* part6   = ws + OFF_PART6;
  float* sraw    = ws + OFF_SRAW;
  float* hbuf    = ws + OFF_HBUF;
  float* slot_out= ws + OFF_SLOT;

  ka_logits<<<512, 256, 0, stream>>>(x, Wd, part1);
  kb_router<<<128, 256, 0, stream>>>(part1, num, csump, combine, out + O_GATE,
                                     out + O_TOPI, out + O_TOPW, musump, entp);
  kd_slotin<<<512, 256, 0, stream>>>(x, num, csump, musump, entp, Wd,
                                     part6, out + O_DISP, out + O_LOSS,
                                     out + O_MU, out + O_ENTR);
  ke_sraw<<<256, 256, 0, stream>>>(part6, sraw);
  kf_h<<<512, 256, 0, stream>>>(sraw, W1, b1, csump, hbuf);
  kg_so<<<512, 256, 0, stream>>>(hbuf, W2, b2, slot_out);
  kh_out<<<1024, 256, 0, stream>>>(slot_out, combine, out + O_OUT);
}